// Round 1
// baseline (2810.154 us; speedup 1.0000x reference)
//
#include <hip/hip_runtime.h>
#include <math.h>

// Multislice gradient step on MI355X.
// 1024x1024 complex fp32 FFTs, radix-2 in LDS, DIF(fwd)+DIT(inv) pairing so all
// frequency-domain multiplies happen in bit-reversed order (kernels pre-permuted).
// Each _prop = 3 passes; pass2 keeps FFT*kern*IFFT LDS-resident.

#define NN (1024*1024)
#define ROWS 4
#define KAPPA 40.840704496667314f
#define TWO_PI_F 6.2831853071795865f
#define DFX_D 0.0030048076923076925   // 1/(0.325*1024) in double

#define PRE_NONE 0
#define PRE_T 1
#define PRE_PWT 2
#define PRE_RESID 3
#define PRE_GRAD 4
#define PRE_T_WP 5

__device__ __forceinline__ float2 cmulf(float2 a, float2 b){
    return make_float2(a.x*b.x - a.y*b.y, a.x*b.y + a.y*b.x);
}
__device__ __forceinline__ float2 cmulcj(float2 a, float2 b){ // a * conj(b)
    return make_float2(a.x*b.x + a.y*b.y, a.y*b.x - a.x*b.y);
}

__device__ __forceinline__ void fill_tw(float2* tw, int tid){
    for (int k = tid; k < 512; k += 256){
        float ang = -(float)k * (TWO_PI_F/1024.0f);
        float s, c; __sincosf(ang, &s, &c);
        tw[k] = make_float2(c, s);
    }
}

// in-place DIF radix-2 over ROWS independent 1024-pt lines; output bit-reversed
__device__ void dif_fwd(float2* lds, const float2* tw, int tid){
    for (int s = 0; s < 10; ++s){
        __syncthreads();
        const int half = 512 >> s;
        #pragma unroll
        for (int k = 0; k < 8; ++k){
            int g   = tid + (k<<8);
            int row = g >> 9;
            int pos = g & 511;
            int j   = pos & (half-1);
            int blk = pos >> (9 - s);
            int i0  = (row << 10) + (blk << (10 - s)) + j;
            int i1  = i0 + half;
            float2 a = lds[i0], b = lds[i1];
            float2 w = tw[j << s];
            lds[i0] = make_float2(a.x+b.x, a.y+b.y);
            float2 d = make_float2(a.x-b.x, a.y-b.y);
            lds[i1] = cmulf(d, w);
        }
    }
    __syncthreads();
}

// positional inverse of dif_fwd: consumes bit-reversed, produces natural (needs *1/1024)
__device__ void dit_inv(float2* lds, const float2* tw, int tid){
    for (int s = 9; s >= 0; --s){
        __syncthreads();
        const int half = 512 >> s;
        #pragma unroll
        for (int k = 0; k < 8; ++k){
            int g   = tid + (k<<8);
            int row = g >> 9;
            int pos = g & 511;
            int j   = pos & (half-1);
            int blk = pos >> (9 - s);
            int i0  = (row << 10) + (blk << (10 - s)) + j;
            int i1  = i0 + half;
            float2 y0 = lds[i0], y1 = lds[i1];
            float2 w  = tw[j << s];
            float2 b  = cmulcj(y1, w);
            lds[i0] = make_float2(y0.x+b.x, y0.y+b.y);
            lds[i1] = make_float2(y0.x-b.x, y0.y-b.y);
        }
    }
    __syncthreads();
}

// ---- frequency-domain kernels, pre-permuted: K2[j*1024+i] = kern[brev(i), brev(j)] ----
__global__ void __launch_bounds__(256) k_kern(float2* __restrict__ kp,
                                              float2* __restrict__ kf,
                                              float2* __restrict__ kpup){
    int idx = blockIdx.x*256 + threadIdx.x;
    int j = idx >> 10, i = idx & 1023;
    int a = __brev((unsigned)i) >> 22;
    int b = __brev((unsigned)j) >> 22;
    double fa = (double)(a - (a >= 512 ? 1024 : 0)) * DFX_D;
    double fb = (double)(b - (b >= 512 ? 1024 : 0)) * DFX_D;
    double urr = fa*fa + fb*fb;
    const double cut = (0.65/0.5)*(0.65/0.5);
    float2 p = make_float2(0.f,0.f), f = make_float2(0.f,0.f), pp = make_float2(0.f,0.f);
    if (urr < cut){
        double kz = sqrt(fmax(4.0 - urr, 0.0));       // (1/WL)^2 = 4
        double s1, c1, s2, c2;
        sincos(6.283185307179586 * 3.25    * kz, &s1, &c1);   // PROPKERN  (dz=+3.25)
        sincos(6.283185307179586 * -24.375 * kz, &s2, &c2);   // FOCUS (dz=-24.375)
        p  = make_float2((float)c1, (float)s1);
        f  = make_float2((float)c2, (float)s2);
        pp = make_float2(1.f, 0.f);
    }
    kp[idx] = p; kf[idx] = f; kpup[idx] = pp;
}

// ---- T = exp(i*kappa*O), planar per slice ----
__global__ void __launch_bounds__(256) k_T(const float4* __restrict__ x,
                                           float2* __restrict__ T){
    int idx = blockIdx.x*256 + threadIdx.x;       // (r,c)
    const float4* xp = x + (size_t)idx*8;
    float4 v[8];
    #pragma unroll
    for (int k=0;k<8;++k) v[k] = xp[k];
    const float* fr = (const float*)v;            // [0..15]=Re(O) z, [16..31]=Im(O) z
    #pragma unroll
    for (int z=0; z<16; ++z){
        float Or = fr[z], Oi = fr[16+z];
        float amp = __expf(-KAPPA*Oi);
        float s, c; __sincosf(KAPPA*Or, &s, &c);
        T[(size_t)z*NN + idx] = make_float2(amp*c, amp*s);
    }
}

// ---- pass1: (optional premultiply) + row DIF + transposed write ----
__global__ void __launch_bounds__(256) k_pass1(
    const float2* __restrict__ src, float2* __restrict__ dst,
    const float2* __restrict__ Ts, const float2* __restrict__ Us,
    float2* __restrict__ gout, const float* __restrict__ meas,
    const float* __restrict__ nail, float2* __restrict__ preout, int mode)
{
    __shared__ float2 lds[ROWS*1024];
    __shared__ float2 tw[512];
    const int tid = threadIdx.x;
    fill_tw(tw, tid);
    const int r0 = blockIdx.x * ROWS;
    const size_t base = (size_t)r0 * 1024;
    float t0 = 0.f, t1 = 0.f;
    if (mode == PRE_PWT){
        float dfx = (float)DFX_D;
        t0 = rintf(nail[0]*2.0f/dfx)*dfx;     // na/WL = na*2
        t1 = rintf(nail[1]*2.0f/dfx)*dfx;
    }
    #pragma unroll
    for (int k = 0; k < 8; ++k){
        int p = tid + (k<<8);                 // float4 index within block tile
        size_t q4 = base/2 + p;
        float2 v0, v1;
        if (mode != PRE_PWT){
            float4 sv = ((const float4*)src)[q4];
            v0 = make_float2(sv.x, sv.y); v1 = make_float2(sv.z, sv.w);
        }
        if (mode == PRE_T || mode == PRE_T_WP){
            float4 tv = ((const float4*)Ts)[q4];
            v0 = cmulf(v0, make_float2(tv.x, tv.y));
            v1 = cmulf(v1, make_float2(tv.z, tv.w));
            if (mode == PRE_T_WP)
                ((float4*)preout)[q4] = make_float4(v0.x, v0.y, v1.x, v1.y);
        } else if (mode == PRE_PWT){
            float4 tv = ((const float4*)Ts)[q4];
            int e0 = p << 1;
            int row = e0 >> 10;
            int col = e0 & 1023;
            float yv = (float)((r0 + row) - 512) * 0.325f;
            float x0 = (float)(col - 512) * 0.325f;
            float x1 = x0 + 0.325f;
            float ph0 = TWO_PI_F * (t0*x0 + t1*yv);
            float ph1 = TWO_PI_F * (t0*x1 + t1*yv);
            float s0, c0, s1, c1;
            sincosf(ph0, &s0, &c0);
            sincosf(ph1, &s1, &c1);
            v0 = cmulf(make_float2(c0, s0), make_float2(tv.x, tv.y));
            v1 = cmulf(make_float2(c1, s1), make_float2(tv.z, tv.w));
        } else if (mode == PRE_RESID){
            float2 mm = ((const float2*)meas)[q4];
            float a0 = fmaxf(sqrtf(v0.x*v0.x + v0.y*v0.y), 1e-30f);
            float f0 = 1.0f - sqrtf(mm.x)/a0;
            v0.x *= f0; v0.y *= f0;
            float a1 = fmaxf(sqrtf(v1.x*v1.x + v1.y*v1.y), 1e-30f);
            float f1 = 1.0f - sqrtf(mm.y)/a1;
            v1.x *= f1; v1.y *= f1;
        } else if (mode == PRE_GRAD){
            float4 tv = ((const float4*)Ts)[q4];
            float4 uv = ((const float4*)Us)[q4];
            float2 p0 = cmulcj(v0, make_float2(tv.x, tv.y));   // ubp*conj(T)
            float2 p1 = cmulcj(v1, make_float2(tv.z, tv.w));
            float2 g0 = cmulcj(p0, make_float2(uv.x, uv.y));   // *conj(u)
            float2 g1 = cmulcj(p1, make_float2(uv.z, uv.w));
            // * conj(K) = -i*kappa:  (-i)(x+iy) = (y, -x)
            ((float4*)gout)[q4] = make_float4(KAPPA*g0.y, -KAPPA*g0.x,
                                              KAPPA*g1.y, -KAPPA*g1.x);
            v0 = p0; v1 = p1;
        }
        int e = p << 1;
        lds[e] = v0; lds[e+1] = v1;
    }
    dif_fwd(lds, tw, tid);
    #pragma unroll
    for (int k = 0; k < 4; ++k){
        int c = tid + (k<<8);
        float2 a0 = lds[c],      a1 = lds[1024+c];
        float2 a2 = lds[2048+c], a3 = lds[3072+c];
        float4* d4 = (float4*)(dst + (size_t)c*1024 + r0);
        d4[0] = make_float4(a0.x, a0.y, a1.x, a1.y);
        d4[1] = make_float4(a2.x, a2.y, a3.x, a3.y);
    }
}

// ---- pass2: DIF + pointwise kernel (bitrev order) + DIT inverse, transposed write ----
__global__ void __launch_bounds__(256) k_pass2(const float2* __restrict__ src,
                                               float2* __restrict__ dst,
                                               const float2* __restrict__ km, int conjk)
{
    __shared__ float2 lds[ROWS*1024];
    __shared__ float2 tw[512];
    const int tid = threadIdx.x;
    fill_tw(tw, tid);
    const int r0 = blockIdx.x * ROWS;
    const size_t base = (size_t)r0 * 1024;
    #pragma unroll
    for (int k=0;k<8;++k){
        int p = tid + (k<<8);
        float4 sv = ((const float4*)src)[base/2 + p];
        int e = p<<1;
        lds[e]   = make_float2(sv.x, sv.y);
        lds[e+1] = make_float2(sv.z, sv.w);
    }
    dif_fwd(lds, tw, tid);
    float sgn = conjk ? -1.0f : 1.0f;
    #pragma unroll
    for (int k=0;k<8;++k){
        int p = tid + (k<<8);
        float4 kv = ((const float4*)km)[base/2 + p];
        int e = p<<1;
        lds[e]   = cmulf(lds[e],   make_float2(kv.x, sgn*kv.y));
        lds[e+1] = cmulf(lds[e+1], make_float2(kv.z, sgn*kv.w));
    }
    dit_inv(lds, tw, tid);
    const float s = 1.0f/1024.0f;
    #pragma unroll
    for (int k=0;k<4;++k){
        int c = tid + (k<<8);
        float2 a0 = lds[c],      a1 = lds[1024+c];
        float2 a2 = lds[2048+c], a3 = lds[3072+c];
        float4* d4 = (float4*)(dst + (size_t)c*1024 + r0);
        d4[0] = make_float4(a0.x*s, a0.y*s, a1.x*s, a1.y*s);
        d4[1] = make_float4(a2.x*s, a2.y*s, a3.x*s, a3.y*s);
    }
}

// ---- pass3: DIT inverse + optional divide-by-T, natural write ----
__global__ void __launch_bounds__(256) k_pass3(const float2* __restrict__ src,
                                               float2* __restrict__ dst,
                                               const float2* __restrict__ Ts, int divt)
{
    __shared__ float2 lds[ROWS*1024];
    __shared__ float2 tw[512];
    const int tid = threadIdx.x;
    fill_tw(tw, tid);
    const int r0 = blockIdx.x * ROWS;
    const size_t base = (size_t)r0 * 1024;
    #pragma unroll
    for (int k=0;k<8;++k){
        int p = tid + (k<<8);
        float4 sv = ((const float4*)src)[base/2 + p];
        int e = p<<1;
        lds[e]   = make_float2(sv.x, sv.y);
        lds[e+1] = make_float2(sv.z, sv.w);
    }
    dit_inv(lds, tw, tid);
    const float s = 1.0f/1024.0f;
    #pragma unroll
    for (int k=0;k<8;++k){
        int p = tid + (k<<8);
        int e = p<<1;
        float2 v0 = make_float2(lds[e].x*s,   lds[e].y*s);
        float2 v1 = make_float2(lds[e+1].x*s, lds[e+1].y*s);
        if (divt){
            float4 tv = ((const float4*)Ts)[base/2 + p];
            float2 ta = make_float2(tv.x, tv.y);
            float2 tb = make_float2(tv.z, tv.w);
            float ia = 1.0f/(ta.x*ta.x + ta.y*ta.y);
            float ib = 1.0f/(tb.x*tb.x + tb.y*tb.y);
            v0 = cmulcj(v0, ta); v0.x *= ia; v0.y *= ia;
            v1 = cmulcj(v1, tb); v1.x *= ib; v1.y *= ib;
        }
        ((float4*)dst)[base/2 + p] = make_float4(v0.x, v0.y, v1.x, v1.y);
    }
}

__global__ void __launch_bounds__(256) k_grad0(const float2* __restrict__ Bp,
                                               const float2* __restrict__ Up,
                                               const float2* __restrict__ Tp,
                                               float2* __restrict__ Gp){
    int idx = blockIdx.x*256 + threadIdx.x;
    float2 b = Bp[idx], u = Up[idx], t = Tp[idx];
    float2 p = cmulcj(b, t);
    float2 q = cmulcj(p, u);
    Gp[idx] = make_float2(KAPPA*q.y, -KAPPA*q.x);
}

__global__ void __launch_bounds__(256) k_merge(const float4* __restrict__ x,
                                               const float2* __restrict__ G,
                                               const float* __restrict__ alpha,
                                               float4* __restrict__ out){
    int idx = blockIdx.x*256 + threadIdx.x;
    float al = alpha[0];
    const float4* xp = x + (size_t)idx*8;
    float4 xv[8];
    #pragma unroll
    for (int k=0;k<8;++k) xv[k] = xp[k];
    const float* fx = (const float*)xv;
    float o[32];
    #pragma unroll
    for (int z=0;z<16;++z){
        float2 g = G[(size_t)z*NN + idx];
        o[z]    = fx[z]    - al*g.x;
        o[16+z] = fx[16+z] - al*g.y;
    }
    float4* op = out + (size_t)idx*8;
    #pragma unroll
    for (int k=0;k<8;++k)
        op[k] = make_float4(o[4*k], o[4*k+1], o[4*k+2], o[4*k+3]);
}

extern "C" void kernel_launch(void* const* d_in, const int* in_sizes, int n_in,
                              void* d_out, int out_size, void* d_ws, size_t ws_size,
                              hipStream_t stream)
{
    const float* x     = (const float*)d_in[0];
    const float* meas  = (const float*)d_in[1];
    const float* nail  = (const float*)d_in[2];
    const float* alpha = (const float*)d_in[3];

    if (ws_size < (size_t)24*NN*sizeof(float2)) return;   // need 192 MiB scratch

    float2* W   = (float2*)d_ws;
    float2* T   = W;                              // 16 planes (also reused as merge output)
    float2* KP  = W + (size_t)16*NN;
    float2* KF  = W + (size_t)17*NN;
    float2* KPU = W + (size_t)18*NN;
    float2* U   = W + (size_t)19*NN;
    float2* V   = W + (size_t)20*NN;
    float2* B   = W + (size_t)21*NN;
    float2* TA  = W + (size_t)22*NN;
    float2* TB  = W + (size_t)23*NN;
    float2* G   = (float2*)d_out;                 // 16 planes of gradient scratch

    k_kern<<<4096, 256, 0, stream>>>(KP, KF, KPU);
    k_T   <<<4096, 256, 0, stream>>>((const float4*)x, T);

    auto P1 = [&](const float2* s, const float2* Tz, const float2* Uu, float2* g,
                  const float* ms, const float* na, float2* pre, int mode){
        k_pass1<<<256, 256, 0, stream>>>(s, TA, Tz, Uu, g, ms, na, pre, mode);
    };
    auto P2 = [&](const float2* km, int cj){
        k_pass2<<<256, 256, 0, stream>>>(TA, TB, km, cj);
    };
    auto P3 = [&](float2* d, const float2* Tz, int divt){
        k_pass3<<<256, 256, 0, stream>>>(TB, d, Tz, divt);
    };

    // ---------- forward multislice ----------
    P1(nullptr, T, nullptr, nullptr, nullptr, nail, nullptr, PRE_PWT);       // u = pw*T0
    P2(KP, 0); P3(U, nullptr, 0);
    for (int z = 1; z < 15; ++z){
        P1(U, T + (size_t)z*NN, nullptr, nullptr, nullptr, nullptr, nullptr, PRE_T);
        P2(KP, 0); P3(U, nullptr, 0);
    }
    // refocus prop, premultiply by T15 and persist u_final into U
    P1(U, T + (size_t)15*NN, nullptr, nullptr, nullptr, nullptr, U, PRE_T_WP);
    P2(KF, 0); P3(V, nullptr, 0);
    // pupil prop
    P1(V, nullptr, nullptr, nullptr, nullptr, nullptr, nullptr, PRE_NONE);
    P2(KPU, 0); P3(V, nullptr, 0);
    // residual + conj(pupil) prop
    P1(V, nullptr, nullptr, nullptr, meas, nullptr, nullptr, PRE_RESID);
    P2(KPU, 1); P3(B, nullptr, 0);
    // conj(focus) prop
    P1(B, nullptr, nullptr, nullptr, nullptr, nullptr, nullptr, PRE_NONE);
    P2(KF, 1); P3(B, nullptr, 0);

    // ---------- reverse slice loop ----------
    for (int zz = 15; zz >= 1; --zz){
        // grad emission fused with FFT of ubp*conj(T[zz]); prop with conj(PROPKERN)
        P1(B, T + (size_t)zz*NN, U, G + (size_t)zz*NN, nullptr, nullptr, nullptr, PRE_GRAD);
        P2(KP, 1); P3(B, nullptr, 0);
        // u back-prop + divide by T[zz-1]
        P1(U, nullptr, nullptr, nullptr, nullptr, nullptr, nullptr, PRE_NONE);
        P2(KP, 1); P3(U, T + (size_t)(zz-1)*NN, 1);
    }
    k_grad0<<<4096, 256, 0, stream>>>(B, U, T, G);

    // ---------- merge: out = x - alpha*g  (write to ws, then d2d into d_out) ----------
    k_merge<<<4096, 256, 0, stream>>>((const float4*)x, G, alpha, (float4*)T);
    hipMemcpyAsync(d_out, T, (size_t)16*NN*sizeof(float2),
                   hipMemcpyDeviceToDevice, stream);
}

// Round 2
// 1898.986 us; speedup vs baseline: 1.4798x; 1.4798x over previous
//
#include <hip/hip_runtime.h>
#include <math.h>

// Multislice gradient step. 1024-pt complex fp32 FFTs: 7 LDS radix-2 stages +
// radix-8 register tail; DIF(fwd)+DIT(inv) so freq-domain multiplies happen in
// bit-reversed order (kernels pre-permuted, pupil computed exactly via ints).
// All chain junctions fused (DIT + pointwise + DIF in one kernel); reverse loop
// processes B- and U-chains per-tile in one block (T-cancellation: grad needs
// only the undivided U DIT output, so U never hits HBM in the reverse loop).

#define NN (1024*1024)
#define KAPPA 40.840704496667314f
#define TWO_PI_F 6.2831853071795865f
#define DFX_D 0.0030048076923076925
#define RRCUT 187177            // ra*ra+rb*rb <= RRCUT  <=>  urr < (NA/WL)^2 (exact, 0.37 margin)
#define PADI(i) ((i) + ((i)>>4))

#define JT 0
#define JT_WP 1
#define JN 2
#define JRESID 3

__device__ __forceinline__ float2 cmulf(float2 a, float2 b){
    return make_float2(a.x*b.x - a.y*b.y, a.x*b.y + a.y*b.x);
}
__device__ __forceinline__ float2 cmulcj(float2 a, float2 b){ // a * conj(b)
    return make_float2(a.x*b.x + a.y*b.y, a.y*b.x - a.x*b.y);
}
__device__ __forceinline__ float2 f2add(float2 a, float2 b){ return make_float2(a.x+b.x, a.y+b.y); }
__device__ __forceinline__ float2 f2sub(float2 a, float2 b){ return make_float2(a.x-b.x, a.y-b.y); }

__device__ __forceinline__ void fill_tw(float2* tw, int tid){
    #pragma unroll
    for (int k = tid; k < 512; k += 256){
        float s, c; sincosf(-(float)k * (TWO_PI_F/1024.0f), &s, &c);
        tw[k] = make_float2(c, s);
    }
}

// ---- 7 LDS radix-2 DIF stages (half=512..8) over 2 rows of 1024 ----
__device__ void dif_lds7(float2* lds, const float2* tw, int tid){
    for (int s = 0; s < 7; ++s){
        __syncthreads();
        const int half = 512 >> s;
        #pragma unroll
        for (int k = 0; k < 4; ++k){
            int g = tid + (k<<8);
            int row = g >> 9, pos = g & 511;
            int j = pos & (half-1);
            int blk = pos >> (9-s);
            int i0 = (row<<10) + (blk << (10-s)) + j;
            int p0 = PADI(i0), p1 = PADI(i0+half);
            float2 a = lds[p0], b = lds[p1];
            float2 w = tw[j<<s];
            lds[p0] = f2add(a,b);
            lds[p1] = cmulf(f2sub(a,b), w);
        }
    }
}
// ---- 7 LDS radix-2 DIT stages (half=8..512), positional inverse ----
__device__ void dit_lds7(float2* lds, const float2* tw, int tid){
    for (int s = 6; s >= 0; --s){
        __syncthreads();
        const int half = 512 >> s;
        #pragma unroll
        for (int k = 0; k < 4; ++k){
            int g = tid + (k<<8);
            int row = g >> 9, pos = g & 511;
            int j = pos & (half-1);
            int blk = pos >> (9-s);
            int i0 = (row<<10) + (blk << (10-s)) + j;
            int p0 = PADI(i0), p1 = PADI(i0+half);
            float2 y0 = lds[p0], y1 = lds[p1];
            float2 b = cmulcj(y1, tw[j<<s]);
            lds[p0] = f2add(y0,b);
            lds[p1] = f2sub(y0,b);
        }
    }
}

// ---- radix-8 register tail: DIF stages half=4,2,1 on 8 consecutive elems ----
__device__ __forceinline__ void dif_reg(float2 r[8]){
    const float C = 0.70710678118654752f;
    float2 a,d;
    a=r[0]; d=f2sub(r[0],r[4]); r[0]=f2add(a,r[4]); r[4]=d;
    a=r[1]; d=f2sub(r[1],r[5]); r[1]=f2add(a,r[5]); r[5]=make_float2(C*(d.x+d.y), C*(d.y-d.x));
    a=r[2]; d=f2sub(r[2],r[6]); r[2]=f2add(a,r[6]); r[6]=make_float2(d.y, -d.x);
    a=r[3]; d=f2sub(r[3],r[7]); r[3]=f2add(a,r[7]); r[7]=make_float2(C*(d.y-d.x), -C*(d.x+d.y));
    a=r[0]; r[0]=f2add(a,r[2]); r[2]=f2sub(a,r[2]);
    a=r[1]; d=f2sub(r[1],r[3]); r[1]=f2add(a,r[3]); r[3]=make_float2(d.y,-d.x);
    a=r[4]; r[4]=f2add(a,r[6]); r[6]=f2sub(a,r[6]);
    a=r[5]; d=f2sub(r[5],r[7]); r[5]=f2add(a,r[7]); r[7]=make_float2(d.y,-d.x);
    a=r[0]; r[0]=f2add(a,r[1]); r[1]=f2sub(a,r[1]);
    a=r[2]; r[2]=f2add(a,r[3]); r[3]=f2sub(a,r[3]);
    a=r[4]; r[4]=f2add(a,r[5]); r[5]=f2sub(a,r[5]);
    a=r[6]; r[6]=f2add(a,r[7]); r[7]=f2sub(a,r[7]);
}
// ---- radix-8 register head: DIT stages half=1,2,4 (conj twiddles) ----
__device__ __forceinline__ void dit_reg(float2 r[8]){
    const float C = 0.70710678118654752f;
    float2 a,b,t;
    a=r[0]; r[0]=f2add(a,r[1]); r[1]=f2sub(a,r[1]);
    a=r[2]; r[2]=f2add(a,r[3]); r[3]=f2sub(a,r[3]);
    a=r[4]; r[4]=f2add(a,r[5]); r[5]=f2sub(a,r[5]);
    a=r[6]; r[6]=f2add(a,r[7]); r[7]=f2sub(a,r[7]);
    a=r[0]; r[0]=f2add(a,r[2]); r[2]=f2sub(a,r[2]);
    a=r[1]; t=r[3]; b=make_float2(-t.y, t.x); r[1]=f2add(a,b); r[3]=f2sub(a,b);
    a=r[4]; r[4]=f2add(a,r[6]); r[6]=f2sub(a,r[6]);
    a=r[5]; t=r[7]; b=make_float2(-t.y, t.x); r[5]=f2add(a,b); r[7]=f2sub(a,b);
    a=r[0]; r[0]=f2add(a,r[4]); r[4]=f2sub(a,r[4]);
    a=r[1]; t=r[5]; b=make_float2(C*(t.x-t.y), C*(t.x+t.y)); r[1]=f2add(a,b); r[5]=f2sub(a,b);
    a=r[2]; t=r[6]; b=make_float2(-t.y, t.x); r[2]=f2add(a,b); r[6]=f2sub(a,b);
    a=r[3]; t=r[7]; b=make_float2(-C*(t.x+t.y), C*(t.x-t.y)); r[3]=f2add(a,b); r[7]=f2sub(a,b);
}

__device__ __forceinline__ void load8(const float2* p, int tid, float2 r[8]){
    const float4* s4 = (const float4*)p + tid*4;
    #pragma unroll
    for (int k=0;k<4;++k){
        float4 v = s4[k];
        r[2*k]   = make_float2(v.x, v.y);
        r[2*k+1] = make_float2(v.z, v.w);
    }
}
__device__ __forceinline__ void store8(float2* lds, int tid, const float2 r[8]){
    #pragma unroll
    for (int m=0;m<8;++m) lds[PADI(8*tid+m)] = r[m];
}
__device__ __forceinline__ void load8_lds(const float2* lds, int tid, float2 r[8]){
    #pragma unroll
    for (int m=0;m<8;++m) r[m] = lds[PADI(8*tid+m)];
}
__device__ __forceinline__ void twrite(const float2* lds, int tid, float2* dst, int r0, float s){
    #pragma unroll
    for (int k=0;k<4;++k){
        int c = tid + (k<<8);
        float2 a0 = lds[PADI(c)], a1 = lds[PADI(1024+c)];
        ((float4*)(dst + ((size_t)c<<10) + r0))[0] =
            make_float4(a0.x*s, a0.y*s, a1.x*s, a1.y*s);
    }
}

// ---- freq-domain kernels, pre-permuted to bitrev x bitrev ----
__global__ void __launch_bounds__(256) k_kern(float2* __restrict__ kp,
                                              float2* __restrict__ kf){
    int idx = blockIdx.x*256 + threadIdx.x;
    int j = idx >> 10, i = idx & 1023;
    int a = __brev((unsigned)i) >> 22;
    int b = __brev((unsigned)j) >> 22;
    int ra = a - (a >= 512 ? 1024 : 0);
    int rb = b - (b >= 512 ? 1024 : 0);
    int rr = ra*ra + rb*rb;
    float2 p = make_float2(0.f,0.f), f = make_float2(0.f,0.f);
    if (rr <= RRCUT){
        double urr = (double)rr * (DFX_D*DFX_D);
        double kz = sqrt(4.0 - urr);
        double s1,c1,s2,c2;
        sincos(6.283185307179586 * 3.25    * kz, &s1, &c1);
        sincos(6.283185307179586 * -24.375 * kz, &s2, &c2);
        p = make_float2((float)c1,(float)s1);
        f = make_float2((float)c2,(float)s2);
    }
    kp[idx] = p; kf[idx] = f;
}

__global__ void __launch_bounds__(256) k_T(const float4* __restrict__ x,
                                           float2* __restrict__ T){
    int idx = blockIdx.x*256 + threadIdx.x;
    const float4* xp = x + (size_t)idx*8;
    float4 v[8];
    #pragma unroll
    for (int k=0;k<8;++k) v[k] = xp[k];
    const float* fr = (const float*)v;
    #pragma unroll
    for (int z=0; z<16; ++z){
        float amp = __expf(-KAPPA*fr[16+z]);
        float s, c; __sincosf(KAPPA*fr[z], &s, &c);
        T[(size_t)z*NN + idx] = make_float2(amp*c, amp*s);
    }
}

// ---- chain head: u = planewave * T0, row DIF, transposed write ----
__global__ void __launch_bounds__(256) k_head(float2* __restrict__ dst,
                                              const float2* __restrict__ T0,
                                              const float* __restrict__ nail){
    __shared__ float2 lds[2176];
    __shared__ float2 tw[512];
    const int tid = threadIdx.x;
    fill_tw(tw, tid);
    const int r0 = blockIdx.x * 2;
    const size_t base = (size_t)r0 << 10;
    float dfx = (float)DFX_D;
    float t0 = rintf(nail[0]*2.0f/dfx)*dfx;
    float t1 = rintf(nail[1]*2.0f/dfx)*dfx;
    #pragma unroll
    for (int k=0;k<4;++k){
        int p4 = tid + (k<<8);
        int e = p4<<1;
        int row = e>>10, col = e&1023;
        float yv = (float)((r0+row) - 512) * 0.325f;
        float x0 = (float)(col - 512) * 0.325f;
        float4 tv = ((const float4*)(T0 + base))[p4];
        float s0,c0,s1,c1;
        sincosf(TWO_PI_F*(t0*x0 + t1*yv), &s0, &c0);
        sincosf(TWO_PI_F*(t0*(x0+0.325f) + t1*yv), &s1, &c1);
        lds[PADI(e)]   = cmulf(make_float2(c0,s0), make_float2(tv.x,tv.y));
        lds[PADI(e+1)] = cmulf(make_float2(c1,s1), make_float2(tv.z,tv.w));
    }
    dif_lds7(lds, tw, tid);
    __syncthreads();
    { float2 r[8]; load8_lds(lds, tid, r); dif_reg(r); store8(lds, tid, r); }
    __syncthreads();
    twrite(lds, tid, dst, r0, 1.0f);
}

// ---- pass2: DIF + kern multiply (regs, bitrev) + DIT, transposed write ----
__global__ void __launch_bounds__(256) k_pass2(
    const float2* __restrict__ srcA, float2* __restrict__ dstA,
    const float2* __restrict__ srcB, float2* __restrict__ dstB,
    const float2* __restrict__ km, int conj, int pupil)
{
    __shared__ float2 lds[2176];
    __shared__ float2 tw[512];
    const int tid = threadIdx.x;
    fill_tw(tw, tid);
    int bid = blockIdx.x;
    const float2* src = srcA; float2* dst = dstA;
    if (srcB != nullptr && bid >= 512){ src = srcB; dst = dstB; bid -= 512; }
    const int r0 = bid * 2;
    const size_t base = (size_t)r0 << 10;
    float2 r[8];
    load8(src + base, tid, r);
    store8(lds, tid, r);
    dif_lds7(lds, tw, tid);
    __syncthreads();
    load8_lds(lds, tid, r);
    dif_reg(r);
    int jrow = r0 + ((tid*8)>>10);
    int ib = (tid*8)&1023;
    if (pupil){
        int bb = __brev((unsigned)jrow) >> 22;
        int rb = bb - (bb >= 512 ? 1024 : 0);
        int rb2 = rb*rb;
        #pragma unroll
        for (int m=0;m<8;++m){
            int aa = __brev((unsigned)(ib+m)) >> 22;
            int ra = aa - (aa >= 512 ? 1024 : 0);
            if (ra*ra + rb2 > RRCUT) r[m] = make_float2(0.f,0.f);
        }
    } else {
        const float4* k4 = (const float4*)(km + (((size_t)jrow)<<10) + ib);
        float sg = conj ? -1.0f : 1.0f;
        #pragma unroll
        for (int k=0;k<4;++k){
            float4 kv = k4[k];
            r[2*k]   = cmulf(r[2*k],   make_float2(kv.x, sg*kv.y));
            r[2*k+1] = cmulf(r[2*k+1], make_float2(kv.z, sg*kv.w));
        }
    }
    dit_reg(r);
    store8(lds, tid, r);
    dit_lds7(lds, tw, tid);
    __syncthreads();
    twrite(lds, tid, dst, r0, 1.0f/1024.0f);
}

// ---- fused junction: DIT + pointwise + DIF ----
__global__ void __launch_bounds__(256) k_junc(
    const float2* __restrict__ src, float2* __restrict__ dst,
    const float2* __restrict__ Tz, float2* __restrict__ wp,
    const float* __restrict__ meas, int mode)
{
    __shared__ float2 lds[2176];
    __shared__ float2 tw[512];
    const int tid = threadIdx.x;
    fill_tw(tw, tid);
    const int r0 = blockIdx.x * 2;
    const size_t base = (size_t)r0 << 10;
    const float S = 1.0f/1024.0f;
    { float2 r[8]; load8(src + base, tid, r); dit_reg(r); store8(lds, tid, r); }
    dit_lds7(lds, tw, tid);
    __syncthreads();
    #pragma unroll
    for (int k=0;k<8;++k){
        int e = tid + (k<<8);
        size_t g = base + e;
        float2 v = lds[PADI(e)];
        v = make_float2(S*v.x, S*v.y);
        if (mode == JT || mode == JT_WP){
            v = cmulf(v, Tz[g]);
            if (mode == JT_WP) wp[g] = v;
        } else if (mode == JRESID){
            float m = meas[g];
            float aamp = fmaxf(sqrtf(v.x*v.x + v.y*v.y), 1e-30f);
            float f = 1.0f - sqrtf(m)/aamp;
            v.x *= f; v.y *= f;
        }
        lds[PADI(e)] = v;
    }
    dif_lds7(lds, tw, tid);
    __syncthreads();
    { float2 r[8]; load8_lds(lds, tid, r); dif_reg(r); store8(lds, tid, r); }
    __syncthreads();
    twrite(lds, tid, dst, r0, 1.0f);
}

// ---- reverse-loop fused junction: both chains per tile, U stays in LDS ----
__global__ void __launch_bounds__(256) k_rev(
    const float2* __restrict__ srcU, float2* __restrict__ dstU,
    const float2* __restrict__ srcB, float2* __restrict__ dstB,
    const float2* __restrict__ Tz, float2* __restrict__ Gz, int headU)
{
    __shared__ float2 ldsA[2176];
    __shared__ float2 ldsB[2176];
    __shared__ float2 tw[512];
    const int tid = threadIdx.x;
    fill_tw(tw, tid);
    const int r0 = blockIdx.x * 2;
    const size_t base = (size_t)r0 << 10;
    const float S = 1.0f/1024.0f;

    // phase 1: U DIT (or natural load if head) -> ldsA (raw, unscaled)
    if (!headU){
        float2 r[8]; load8(srcU + base, tid, r); dit_reg(r); store8(ldsA, tid, r);
        dit_lds7(ldsA, tw, tid);
    } else {
        #pragma unroll
        for (int k=0;k<4;++k){
            int p4 = tid + (k<<8);
            float4 v = ((const float4*)(srcU + base))[p4];
            int e = p4<<1;
            ldsA[PADI(e)]   = make_float2(v.x,v.y);
            ldsA[PADI(e+1)] = make_float2(v.z,v.w);
        }
    }
    __syncthreads();
    // phase 2: divided U field -> ldsB (ldsA untouched)
    #pragma unroll
    for (int k=0;k<8;++k){
        int e = tid + (k<<8);
        size_t g = base + e;
        float2 w = ldsA[PADI(e)];
        float2 v;
        if (headU) v = w;
        else {
            w = make_float2(S*w.x, S*w.y);
            float2 t = Tz[g];
            float inv = 1.0f/(t.x*t.x + t.y*t.y);
            float2 wc = cmulcj(w, t);
            v = make_float2(wc.x*inv, wc.y*inv);
        }
        ldsB[PADI(e)] = v;
    }
    // phase 3: U DIF -> transposed write dstU
    dif_lds7(ldsB, tw, tid);
    __syncthreads();
    { float2 r[8]; load8_lds(ldsB, tid, r); dif_reg(r); store8(ldsB, tid, r); }
    __syncthreads();
    twrite(ldsB, tid, dstU, r0, 1.0f);
    __syncthreads();
    // phase 4: B DIT -> ldsB
    { float2 r[8]; load8(srcB + base, tid, r); dit_reg(r); store8(ldsB, tid, r); }
    dit_lds7(ldsB, tw, tid);
    __syncthreads();
    // phase 5: grad emit + premult conj(T)
    #pragma unroll
    for (int k=0;k<8;++k){
        int e = tid + (k<<8);
        size_t g = base + e;
        float2 b = ldsB[PADI(e)];
        b = make_float2(S*b.x, S*b.y);
        float2 t = Tz[g];
        float2 w = ldsA[PADI(e)];
        float2 q;
        if (headU){
            q = cmulcj(cmulcj(b, w), t);           // b*conj(u15)*conj(T15)
        } else {
            float2 ws = make_float2(S*w.x, S*w.y); // = u_zz * T_zz
            q = cmulcj(b, ws);                     // T cancels
        }
        Gz[g] = make_float2(KAPPA*q.y, -KAPPA*q.x);
        ldsB[PADI(e)] = cmulcj(b, t);
    }
    // phase 6: B DIF -> transposed write dstB
    dif_lds7(ldsB, tw, tid);
    __syncthreads();
    { float2 r[8]; load8_lds(ldsB, tid, r); dif_reg(r); store8(ldsB, tid, r); }
    __syncthreads();
    twrite(ldsB, tid, dstB, r0, 1.0f);
}

// ---- tail: finish both chains, emit grad[0] directly ----
__global__ void __launch_bounds__(256) k_tail(
    const float2* __restrict__ srcU, const float2* __restrict__ srcB,
    float2* __restrict__ G0)
{
    __shared__ float2 ldsA[2176];
    __shared__ float2 ldsB[2176];
    __shared__ float2 tw[512];
    const int tid = threadIdx.x;
    fill_tw(tw, tid);
    const int r0 = blockIdx.x * 2;
    const size_t base = (size_t)r0 << 10;
    const float S = 1.0f/1024.0f;
    { float2 r[8]; load8(srcU + base, tid, r); dit_reg(r); store8(ldsA, tid, r); }
    dit_lds7(ldsA, tw, tid);
    { float2 r[8]; load8(srcB + base, tid, r); dit_reg(r); store8(ldsB, tid, r); }
    dit_lds7(ldsB, tw, tid);
    __syncthreads();
    #pragma unroll
    for (int k=0;k<8;++k){
        int e = tid + (k<<8);
        size_t g = base + e;
        float2 b = ldsB[PADI(e)];
        float2 w = ldsA[PADI(e)];
        b = make_float2(S*b.x, S*b.y);
        w = make_float2(S*w.x, S*w.y);
        float2 q = cmulcj(b, w);
        G0[g] = make_float2(KAPPA*q.y, -KAPPA*q.x);
    }
}

__global__ void __launch_bounds__(256) k_merge(const float4* __restrict__ x,
                                               const float2* __restrict__ G,
                                               const float* __restrict__ alpha,
                                               float4* __restrict__ out){
    int idx = blockIdx.x*256 + threadIdx.x;
    float al = alpha[0];
    const float4* xp = x + (size_t)idx*8;
    float4 xv[8];
    #pragma unroll
    for (int k=0;k<8;++k) xv[k] = xp[k];
    const float* fx = (const float*)xv;
    float o[32];
    #pragma unroll
    for (int z=0;z<16;++z){
        float2 g = G[(size_t)z*NN + idx];
        o[z]    = fx[z]    - al*g.x;
        o[16+z] = fx[16+z] - al*g.y;
    }
    float4* op = out + (size_t)idx*8;
    #pragma unroll
    for (int k=0;k<8;++k)
        op[k] = make_float4(o[4*k], o[4*k+1], o[4*k+2], o[4*k+3]);
}

extern "C" void kernel_launch(void* const* d_in, const int* in_sizes, int n_in,
                              void* d_out, int out_size, void* d_ws, size_t ws_size,
                              hipStream_t stream)
{
    const float* x     = (const float*)d_in[0];
    const float* meas  = (const float*)d_in[1];
    const float* nail  = (const float*)d_in[2];
    const float* alpha = (const float*)d_in[3];

    if (ws_size < (size_t)23*NN*sizeof(float2)) return;   // 184 MiB scratch

    float2* W   = (float2*)d_ws;
    float2* T   = W;                       // 16 planes (reused as merge output)
    float2* KP  = W + (size_t)16*NN;
    float2* KF  = W + (size_t)17*NN;
    float2* U0  = W + (size_t)18*NN;
    float2* TAB = W + (size_t)19*NN;
    float2* TBB = W + (size_t)20*NN;
    float2* TAU = W + (size_t)21*NN;
    float2* TBU = W + (size_t)22*NN;
    float2* G   = (float2*)d_out;          // 16 gradient planes (scratch)

    k_kern<<<4096, 256, 0, stream>>>(KP, KF);
    k_T   <<<4096, 256, 0, stream>>>((const float4*)x, T);

    auto P2 = [&](const float2* km, int cj, int pup){
        k_pass2<<<512, 256, 0, stream>>>(TBB, TAB, nullptr, nullptr, km, cj, pup);
    };
    // NOTE: forward p2 reads TBB? No: forward chain alternates TAB->TBB.
    // k_head/k_junc write TAB; p2 reads TAB writes TBB; k_junc reads TBB.
    auto P2f = [&](const float2* km, int cj, int pup){
        k_pass2<<<512, 256, 0, stream>>>(TAB, TBB, nullptr, nullptr, km, cj, pup);
    };
    (void)P2;

    // ---------- forward + backprop mega-chain (B) ----------
    k_head<<<512, 256, 0, stream>>>(TAB, T, nail);
    P2f(KP, 0, 0);
    for (int z = 1; z <= 14; ++z){
        k_junc<<<512, 256, 0, stream>>>(TBB, TAB, T + (size_t)z*NN, nullptr, nullptr, JT);
        P2f(KP, 0, 0);
    }
    k_junc<<<512, 256, 0, stream>>>(TBB, TAB, T + (size_t)15*NN, U0, nullptr, JT_WP);
    P2f(KF, 0, 0);
    k_junc<<<512, 256, 0, stream>>>(TBB, TAB, nullptr, nullptr, nullptr, JN);
    P2f(nullptr, 0, 1);
    k_junc<<<512, 256, 0, stream>>>(TBB, TAB, nullptr, nullptr, meas, JRESID);
    P2f(nullptr, 1, 1);
    k_junc<<<512, 256, 0, stream>>>(TBB, TAB, nullptr, nullptr, nullptr, JN);
    P2f(KF, 1, 0);

    // ---------- reverse loop: paired B/U per tile ----------
    for (int zz = 15; zz >= 1; --zz){
        k_rev<<<512, 256, 0, stream>>>(zz == 15 ? U0 : TBU, TAU, TBB, TAB,
                                       T + (size_t)zz*NN, G + (size_t)zz*NN,
                                       zz == 15 ? 1 : 0);
        k_pass2<<<1024, 256, 0, stream>>>(TAB, TBB, TAU, TBU, KP, 1, 0);
    }
    k_tail<<<512, 256, 0, stream>>>(TBU, TBB, G);

    // ---------- merge + copy back ----------
    k_merge<<<4096, 256, 0, stream>>>((const float4*)x, G, alpha, (float4*)T);
    hipMemcpyAsync(d_out, T, (size_t)16*NN*sizeof(float2),
                   hipMemcpyDeviceToDevice, stream);
}

// Round 3
// 1518.975 us; speedup vs baseline: 1.8500x; 1.2502x over previous
//
#include <hip/hip_runtime.h>
#include <math.h>

// Multislice gradient step. 1024-pt complex fp32 FFT as 3 register-radix-8
// phases (fused radix-2 stages 0-2 / 3-5 / 6-9) with ping-pong LDS exchanges:
// 5-10 barriers/kernel vs 18-24 before. DIF(fwd)+DIT(inv) keep freq-domain
// multiplies in bit-reversed order (kernels pre-permuted). Gradients overwrite
// the dead T planes, so k_merge writes d_out directly (no final memcpy).

#define NN (1024*1024)
#define KAPPA 40.840704496667314f
#define TWO_PI_F 6.2831853071795865f
#define DFX_D 0.0030048076923076925
#define RRCUT 187177
#define F(i) ((i) + ((i)>>4))

#define JT 0
#define JT_WP 1
#define JN 2
#define JRESID 3

__device__ __forceinline__ float2 cmulf(float2 a, float2 b){
    return make_float2(a.x*b.x - a.y*b.y, a.x*b.y + a.y*b.x);
}
__device__ __forceinline__ float2 cmulcj(float2 a, float2 b){ // a * conj(b)
    return make_float2(a.x*b.x + a.y*b.y, a.y*b.x - a.x*b.y);
}
__device__ __forceinline__ float2 f2add(float2 a, float2 b){ return make_float2(a.x+b.x, a.y+b.y); }
__device__ __forceinline__ float2 f2sub(float2 a, float2 b){ return make_float2(a.x-b.x, a.y-b.y); }

__device__ __forceinline__ void fill_tw(float2* tw, int tid){
    #pragma unroll
    for (int k = tid; k < 512; k += 256){
        float s, c; sincosf(-(float)k * (TWO_PI_F/1024.0f), &s, &c);
        tw[k] = make_float2(c, s);
    }
}

// ---------- register phase kernels (positions tracked per comments) ----------
// DIF phase1: stages half=512,256,128 on elements at positions lane+128k
__device__ __forceinline__ void dif_ph1(float2 r[8], const float2* tw, int lane){
    float2 a, d;
    #pragma unroll
    for (int k=0;k<4;++k){
        a=r[k]; d=f2sub(r[k],r[k+4]);
        r[k]=f2add(a,r[k+4]);
        r[k+4]=cmulf(d, tw[lane+128*k]);
    }
    float2 w20 = tw[lane<<1], w21 = tw[(lane+128)<<1];
    a=r[0]; d=f2sub(r[0],r[2]); r[0]=f2add(a,r[2]); r[2]=cmulf(d,w20);
    a=r[1]; d=f2sub(r[1],r[3]); r[1]=f2add(a,r[3]); r[3]=cmulf(d,w21);
    a=r[4]; d=f2sub(r[4],r[6]); r[4]=f2add(a,r[6]); r[6]=cmulf(d,w20);
    a=r[5]; d=f2sub(r[5],r[7]); r[5]=f2add(a,r[7]); r[7]=cmulf(d,w21);
    float2 w3 = tw[lane<<2];
    a=r[0]; d=f2sub(r[0],r[1]); r[0]=f2add(a,r[1]); r[1]=cmulf(d,w3);
    a=r[2]; d=f2sub(r[2],r[3]); r[2]=f2add(a,r[3]); r[3]=cmulf(d,w3);
    a=r[4]; d=f2sub(r[4],r[5]); r[4]=f2add(a,r[5]); r[5]=cmulf(d,w3);
    a=r[6]; d=f2sub(r[6],r[7]); r[6]=f2add(a,r[7]); r[7]=cmulf(d,w3);
}
// DIT phase1': stages half=128,256,512 (inverse of dif_ph1)
__device__ __forceinline__ void dit_ph1(float2 r[8], const float2* tw, int lane){
    float2 a, b;
    float2 w3 = tw[lane<<2];
    a=r[0]; b=cmulcj(r[1],w3); r[0]=f2add(a,b); r[1]=f2sub(a,b);
    a=r[2]; b=cmulcj(r[3],w3); r[2]=f2add(a,b); r[3]=f2sub(a,b);
    a=r[4]; b=cmulcj(r[5],w3); r[4]=f2add(a,b); r[5]=f2sub(a,b);
    a=r[6]; b=cmulcj(r[7],w3); r[6]=f2add(a,b); r[7]=f2sub(a,b);
    float2 w20 = tw[lane<<1], w21 = tw[(lane+128)<<1];
    a=r[0]; b=cmulcj(r[2],w20); r[0]=f2add(a,b); r[2]=f2sub(a,b);
    a=r[1]; b=cmulcj(r[3],w21); r[1]=f2add(a,b); r[3]=f2sub(a,b);
    a=r[4]; b=cmulcj(r[6],w20); r[4]=f2add(a,b); r[6]=f2sub(a,b);
    a=r[5]; b=cmulcj(r[7],w21); r[5]=f2add(a,b); r[7]=f2sub(a,b);
    #pragma unroll
    for (int k=0;k<4;++k){
        a=r[k]; b=cmulcj(r[k+4], tw[lane+128*k]);
        r[k]=f2add(a,b); r[k+4]=f2sub(a,b);
    }
}
// DIF phase2: stages half=64,32,16 on elements at positions 128b+m0+16k
__device__ __forceinline__ void dif_ph2(float2 r[8], const float2* tw, int m0){
    float2 a, d;
    #pragma unroll
    for (int k=0;k<4;++k){
        a=r[k]; d=f2sub(r[k],r[k+4]);
        r[k]=f2add(a,r[k+4]);
        r[k+4]=cmulf(d, tw[(m0+16*k)<<3]);
    }
    float2 w40 = tw[m0<<4], w41 = tw[(m0+16)<<4];
    a=r[0]; d=f2sub(r[0],r[2]); r[0]=f2add(a,r[2]); r[2]=cmulf(d,w40);
    a=r[1]; d=f2sub(r[1],r[3]); r[1]=f2add(a,r[3]); r[3]=cmulf(d,w41);
    a=r[4]; d=f2sub(r[4],r[6]); r[4]=f2add(a,r[6]); r[6]=cmulf(d,w40);
    a=r[5]; d=f2sub(r[5],r[7]); r[5]=f2add(a,r[7]); r[7]=cmulf(d,w41);
    float2 w5 = tw[m0<<5];
    a=r[0]; d=f2sub(r[0],r[1]); r[0]=f2add(a,r[1]); r[1]=cmulf(d,w5);
    a=r[2]; d=f2sub(r[2],r[3]); r[2]=f2add(a,r[3]); r[3]=cmulf(d,w5);
    a=r[4]; d=f2sub(r[4],r[5]); r[4]=f2add(a,r[5]); r[5]=cmulf(d,w5);
    a=r[6]; d=f2sub(r[6],r[7]); r[6]=f2add(a,r[7]); r[7]=cmulf(d,w5);
}
// DIT phase2': stages half=16,32,64
__device__ __forceinline__ void dit_ph2(float2 r[8], const float2* tw, int m0){
    float2 a, b;
    float2 w5 = tw[m0<<5];
    a=r[0]; b=cmulcj(r[1],w5); r[0]=f2add(a,b); r[1]=f2sub(a,b);
    a=r[2]; b=cmulcj(r[3],w5); r[2]=f2add(a,b); r[3]=f2sub(a,b);
    a=r[4]; b=cmulcj(r[5],w5); r[4]=f2add(a,b); r[5]=f2sub(a,b);
    a=r[6]; b=cmulcj(r[7],w5); r[6]=f2add(a,b); r[7]=f2sub(a,b);
    float2 w40 = tw[m0<<4], w41 = tw[(m0+16)<<4];
    a=r[0]; b=cmulcj(r[2],w40); r[0]=f2add(a,b); r[2]=f2sub(a,b);
    a=r[1]; b=cmulcj(r[3],w41); r[1]=f2add(a,b); r[3]=f2sub(a,b);
    a=r[4]; b=cmulcj(r[6],w40); r[4]=f2add(a,b); r[6]=f2sub(a,b);
    a=r[5]; b=cmulcj(r[7],w41); r[5]=f2add(a,b); r[7]=f2sub(a,b);
    #pragma unroll
    for (int k=0;k<4;++k){
        a=r[k]; b=cmulcj(r[k+4], tw[(m0+16*k)<<3]);
        r[k]=f2add(a,b); r[k+4]=f2sub(a,b);
    }
}
// radix-8 tail: DIF stages half=4,2,1 on 8 consecutive elems (verified R2)
__device__ __forceinline__ void dif_reg(float2 r[8]){
    const float C = 0.70710678118654752f;
    float2 a,d;
    a=r[0]; d=f2sub(r[0],r[4]); r[0]=f2add(a,r[4]); r[4]=d;
    a=r[1]; d=f2sub(r[1],r[5]); r[1]=f2add(a,r[5]); r[5]=make_float2(C*(d.x+d.y), C*(d.y-d.x));
    a=r[2]; d=f2sub(r[2],r[6]); r[2]=f2add(a,r[6]); r[6]=make_float2(d.y, -d.x);
    a=r[3]; d=f2sub(r[3],r[7]); r[3]=f2add(a,r[7]); r[7]=make_float2(C*(d.y-d.x), -C*(d.x+d.y));
    a=r[0]; r[0]=f2add(a,r[2]); r[2]=f2sub(a,r[2]);
    a=r[1]; d=f2sub(r[1],r[3]); r[1]=f2add(a,r[3]); r[3]=make_float2(d.y,-d.x);
    a=r[4]; r[4]=f2add(a,r[6]); r[6]=f2sub(a,r[6]);
    a=r[5]; d=f2sub(r[5],r[7]); r[5]=f2add(a,r[7]); r[7]=make_float2(d.y,-d.x);
    a=r[0]; r[0]=f2add(a,r[1]); r[1]=f2sub(a,r[1]);
    a=r[2]; r[2]=f2add(a,r[3]); r[3]=f2sub(a,r[3]);
    a=r[4]; r[4]=f2add(a,r[5]); r[5]=f2sub(a,r[5]);
    a=r[6]; r[6]=f2add(a,r[7]); r[7]=f2sub(a,r[7]);
}
// radix-8 head: DIT stages half=1,2,4 (verified R2)
__device__ __forceinline__ void dit_reg(float2 r[8]){
    const float C = 0.70710678118654752f;
    float2 a,b,t;
    a=r[0]; r[0]=f2add(a,r[1]); r[1]=f2sub(a,r[1]);
    a=r[2]; r[2]=f2add(a,r[3]); r[3]=f2sub(a,r[3]);
    a=r[4]; r[4]=f2add(a,r[5]); r[5]=f2sub(a,r[5]);
    a=r[6]; r[6]=f2add(a,r[7]); r[7]=f2sub(a,r[7]);
    a=r[0]; r[0]=f2add(a,r[2]); r[2]=f2sub(a,r[2]);
    a=r[1]; t=r[3]; b=make_float2(-t.y, t.x); r[1]=f2add(a,b); r[3]=f2sub(a,b);
    a=r[4]; r[4]=f2add(a,r[6]); r[6]=f2sub(a,r[6]);
    a=r[5]; t=r[7]; b=make_float2(-t.y, t.x); r[5]=f2add(a,b); r[7]=f2sub(a,b);
    a=r[0]; r[0]=f2add(a,r[4]); r[4]=f2sub(a,r[4]);
    a=r[1]; t=r[5]; b=make_float2(C*(t.x-t.y), C*(t.x+t.y)); r[1]=f2add(a,b); r[5]=f2sub(a,b);
    a=r[2]; t=r[6]; b=make_float2(-t.y, t.x); r[2]=f2add(a,b); r[6]=f2sub(a,b);
    a=r[3]; t=r[7]; b=make_float2(-C*(t.x+t.y), C*(t.x-t.y)); r[3]=f2add(a,b); r[7]=f2sub(a,b);
}

// ---------- LDS exchange helpers (ro = row*1024 position offset) ----------
__device__ __forceinline__ void st128l(float2* L, int ro, int lane, const float2 r[8]){
    #pragma unroll
    for (int k=0;k<8;++k) L[F(ro + lane + 128*k)] = r[k];
}
__device__ __forceinline__ void ld128l(const float2* L, int ro, int lane, float2 r[8]){
    #pragma unroll
    for (int k=0;k<8;++k) r[k] = L[F(ro + lane + 128*k)];
}
__device__ __forceinline__ void st16l(float2* L, int ro, int lane, const float2 r[8]){
    int b = lane>>4, m0 = lane&15, q = ro + 128*b + m0;
    #pragma unroll
    for (int k=0;k<8;++k) L[F(q + 16*k)] = r[k];
}
__device__ __forceinline__ void ld16l(const float2* L, int ro, int lane, float2 r[8]){
    int b = lane>>4, m0 = lane&15, q = ro + 128*b + m0;
    #pragma unroll
    for (int k=0;k<8;++k) r[k] = L[F(q + 16*k)];
}
__device__ __forceinline__ void st8l(float2* L, int ro, int lane, const float2 r[8]){
    int q = ro + 8*lane;
    #pragma unroll
    for (int i=0;i<8;++i) L[F(q + i)] = r[i];
}
// read after st8l state, fold DIF stage half=8, leaves 8 consecutive (pos 8*lane+i)
__device__ __forceinline__ void ldfold_dif(const float2* L, int ro, int lane,
                                           const float2* tw, float2 r[8]){
    int rr = lane>>1, sub = lane&1, q = ro + 16*rr;
    #pragma unroll
    for (int i=0;i<8;++i){
        float2 x = L[F(q + i)];
        float2 y = L[F(q + 8 + i)];
        r[i] = sub ? cmulf(f2sub(x,y), tw[i<<6]) : f2add(x,y);
    }
}
// read after st8l state, fold DIT stage half=8, leaves stride-16 (pos 128b+m0+16k)
__device__ __forceinline__ void ldfold_dit(const float2* L, int ro, int lane,
                                           const float2* tw, float2 r[8]){
    int b = lane>>4, m0 = lane&15, m0s = m0&7;
    float2 w = tw[m0s<<6];
    int q = ro + 128*b + m0s;
    #pragma unroll
    for (int k=0;k<8;++k){
        float2 x = L[F(q + 16*k)];
        float2 y = L[F(q + 16*k + 8)];
        float2 bb = cmulcj(y, w);
        r[k] = (m0 < 8) ? f2add(x,bb) : f2sub(x,bb);
    }
}
__device__ __forceinline__ void load8g(const float2* src, int lane, float2 r[8]){
    const float4* s4 = (const float4*)src + lane*4;
    #pragma unroll
    for (int m=0;m<4;++m){
        float4 v = s4[m];
        r[2*m]   = make_float2(v.x, v.y);
        r[2*m+1] = make_float2(v.z, v.w);
    }
}
__device__ __forceinline__ void twrite2(const float2* L, int tid, float2* dst,
                                        int r0, float s){
    #pragma unroll
    for (int k=0;k<4;++k){
        int c = tid + (k<<8);
        float2 a0 = L[F(c)], a1 = L[F(1024+c)];
        ((float4*)(dst + ((size_t)c<<10) + r0))[0] =
            make_float4(a0.x*s, a0.y*s, a1.x*s, a1.y*s);
    }
}

// ---------- precompute kernels ----------
__global__ void __launch_bounds__(256) k_kern(float2* __restrict__ kp,
                                              float2* __restrict__ kf){
    int idx = blockIdx.x*256 + threadIdx.x;
    int j = idx >> 10, i = idx & 1023;
    int a = __brev((unsigned)i) >> 22;
    int b = __brev((unsigned)j) >> 22;
    int ra = a - (a >= 512 ? 1024 : 0);
    int rb = b - (b >= 512 ? 1024 : 0);
    int rr = ra*ra + rb*rb;
    float2 p = make_float2(0.f,0.f), f = make_float2(0.f,0.f);
    if (rr <= RRCUT){
        double urr = (double)rr * (DFX_D*DFX_D);
        double kz = sqrt(4.0 - urr);
        double s1,c1,s2,c2;
        sincos(6.283185307179586 * 3.25    * kz, &s1, &c1);
        sincos(6.283185307179586 * -24.375 * kz, &s2, &c2);
        p = make_float2((float)c1,(float)s1);
        f = make_float2((float)c2,(float)s2);
    }
    kp[idx] = p; kf[idx] = f;
}

__global__ void __launch_bounds__(256) k_T(const float4* __restrict__ x,
                                           float2* __restrict__ T){
    int idx = blockIdx.x*256 + threadIdx.x;
    const float4* xp = x + (size_t)idx*8;
    float4 v[8];
    #pragma unroll
    for (int k=0;k<8;++k) v[k] = xp[k];
    const float* fr = (const float*)v;
    #pragma unroll
    for (int z=0; z<16; ++z){
        float amp = __expf(-KAPPA*fr[16+z]);
        float s, c; __sincosf(KAPPA*fr[z], &s, &c);
        T[(size_t)z*NN + idx] = make_float2(amp*c, amp*s);
    }
}

// ---------- chain head: u = planewave*T0, row DIF, transposed write ----------
__global__ void __launch_bounds__(256) k_head(float2* __restrict__ dst,
                                              const float2* __restrict__ T0,
                                              const float* __restrict__ nail){
    __shared__ float2 A[2176], B[2176], tw[512];
    const int tid = threadIdx.x;
    fill_tw(tw, tid);
    const int row = tid>>7, lane = tid&127, ro = row<<10, m0 = lane&15;
    const int r0 = blockIdx.x*2;
    const size_t gbase = ((size_t)(r0+row))<<10;
    float dfx = (float)DFX_D;
    float t0 = rintf(nail[0]*2.0f/dfx)*dfx;
    float t1 = rintf(nail[1]*2.0f/dfx)*dfx;
    float yv = (float)((r0+row) - 512) * 0.325f;
    float2 r[8];
    #pragma unroll
    for (int k=0;k<8;++k){
        int col = lane + 128*k;
        float2 tv = T0[gbase + col];
        float xv = (float)(col - 512) * 0.325f;
        float s0, c0; sincosf(TWO_PI_F*(t0*xv + t1*yv), &s0, &c0);
        r[k] = cmulf(make_float2(c0,s0), tv);
    }
    __syncthreads();                       // tw ready
    dif_ph1(r, tw, lane);
    st128l(A, ro, lane, r); __syncthreads();
    ld16l(A, ro, lane, r); dif_ph2(r, tw, m0);
    st16l(B, ro, lane, r); __syncthreads();
    ldfold_dif(B, ro, lane, tw, r); dif_reg(r);
    st8l(A, ro, lane, r); __syncthreads();
    twrite2(A, tid, dst, r0, 1.0f);
}

// ---------- pass2: col DIF + kern-mult (bitrev) + col DIT, transposed ----------
__global__ void __launch_bounds__(256) k_pass2(
    const float2* __restrict__ srcA, float2* __restrict__ dstA,
    const float2* __restrict__ srcB, float2* __restrict__ dstB,
    const float2* __restrict__ km, int conj, int pupil)
{
    __shared__ float2 A[2176], B[2176], tw[512];
    const int tid = threadIdx.x;
    fill_tw(tw, tid);
    const int row = tid>>7, lane = tid&127, ro = row<<10, m0 = lane&15;
    int bid = blockIdx.x;
    const float2* src = srcA; float2* dst = dstA;
    if (srcB != nullptr && bid >= 512){ src = srcB; dst = dstB; bid -= 512; }
    const int r0 = bid*2;
    const int jrow = r0 + row;
    const float2* srcR = src + (((size_t)r0)<<10) + ro;
    float2 r[8];
    #pragma unroll
    for (int k=0;k<8;++k) r[k] = srcR[lane + 128*k];
    __syncthreads();                       // tw ready
    dif_ph1(r, tw, lane);
    st128l(A, ro, lane, r); __syncthreads();
    ld16l(A, ro, lane, r); dif_ph2(r, tw, m0);
    st16l(B, ro, lane, r); __syncthreads();
    ldfold_dif(B, ro, lane, tw, r); dif_reg(r);
    // pointwise at bitrev positions 8*lane+i of row jrow
    if (pupil){
        int bb = __brev((unsigned)jrow) >> 22;
        int rb = bb - (bb >= 512 ? 1024 : 0);
        int rb2 = rb*rb;
        #pragma unroll
        for (int i=0;i<8;++i){
            int aa = __brev((unsigned)(8*lane+i)) >> 22;
            int ra = aa - (aa >= 512 ? 1024 : 0);
            if (ra*ra + rb2 > RRCUT) r[i] = make_float2(0.f,0.f);
        }
    } else {
        const float4* k4 = (const float4*)(km + (((size_t)jrow)<<10)) + lane*4;
        float sg = conj ? -1.0f : 1.0f;
        #pragma unroll
        for (int m=0;m<4;++m){
            float4 kv = k4[m];
            r[2*m]   = cmulf(r[2*m],   make_float2(kv.x, sg*kv.y));
            r[2*m+1] = cmulf(r[2*m+1], make_float2(kv.z, sg*kv.w));
        }
    }
    dit_reg(r);
    st8l(A, ro, lane, r); __syncthreads();
    ldfold_dit(A, ro, lane, tw, r); dit_ph2(r, tw, m0);
    st16l(B, ro, lane, r); __syncthreads();
    ld128l(B, ro, lane, r); dit_ph1(r, tw, lane);
    st128l(A, ro, lane, r); __syncthreads();
    twrite2(A, tid, dst, r0, 1.0f/1024.0f);
}

// ---------- fused junction: row DIT + pointwise + row DIF ----------
__global__ void __launch_bounds__(256) k_junc(
    const float2* __restrict__ src, float2* __restrict__ dst,
    const float2* __restrict__ Tz, float2* __restrict__ wp,
    const float* __restrict__ meas, int mode)
{
    __shared__ float2 A[2176], B[2176], tw[512];
    const int tid = threadIdx.x;
    fill_tw(tw, tid);
    const int row = tid>>7, lane = tid&127, ro = row<<10, m0 = lane&15;
    const int r0 = blockIdx.x*2;
    const size_t gbase = ((size_t)(r0+row))<<10;
    const float S = 1.0f/1024.0f;
    float2 r[8];
    load8g(src + (((size_t)r0)<<10) + ro, lane, r);
    dit_reg(r);
    st8l(A, ro, lane, r); __syncthreads();
    ldfold_dit(A, ro, lane, tw, r); dit_ph2(r, tw, m0);
    st16l(B, ro, lane, r); __syncthreads();
    ld128l(B, ro, lane, r); dit_ph1(r, tw, lane);
    #pragma unroll
    for (int k=0;k<8;++k){
        size_t g = gbase + lane + 128*k;
        float2 v = make_float2(S*r[k].x, S*r[k].y);
        if (mode == JT || mode == JT_WP){
            v = cmulf(v, Tz[g]);
            if (mode == JT_WP) wp[g] = v;
        } else if (mode == JRESID){
            float m = meas[g];
            float aamp = fmaxf(sqrtf(v.x*v.x + v.y*v.y), 1e-30f);
            float f = 1.0f - sqrtf(m)/aamp;
            v.x *= f; v.y *= f;
        }
        r[k] = v;
    }
    dif_ph1(r, tw, lane);
    st128l(A, ro, lane, r); __syncthreads();
    ld16l(A, ro, lane, r); dif_ph2(r, tw, m0);
    st16l(B, ro, lane, r); __syncthreads();
    ldfold_dif(B, ro, lane, tw, r); dif_reg(r);
    st8l(A, ro, lane, r); __syncthreads();
    twrite2(A, tid, dst, r0, 1.0f);
}

// ---------- reverse junction: both chains per tile; grad -> T plane ----------
__global__ void __launch_bounds__(256) k_rev(
    const float2* __restrict__ srcU, float2* __restrict__ dstU,
    const float2* __restrict__ srcB, float2* __restrict__ dstB,
    float2* __restrict__ Tz, int headU)
{
    __shared__ float2 A[2176], B[2176], tw[512];
    const int tid = threadIdx.x;
    fill_tw(tw, tid);
    const int row = tid>>7, lane = tid&127, ro = row<<10, m0 = lane&15;
    const int r0 = blockIdx.x*2;
    const size_t gbase = ((size_t)(r0+row))<<10;
    const float S = 1.0f/1024.0f;
    float2 u[8], Tg[8], r[8];
    // ---- U chain: DIT (or direct natural load at head) ----
    if (!headU){
        load8g(srcU + (((size_t)r0)<<10) + ro, lane, u);
        dit_reg(u);
        st8l(A, ro, lane, u); __syncthreads();
        ldfold_dit(A, ro, lane, tw, u); dit_ph2(u, tw, m0);
        st16l(B, ro, lane, u); __syncthreads();
        ld128l(B, ro, lane, u); dit_ph1(u, tw, lane);
        #pragma unroll
        for (int k=0;k<8;++k){ u[k].x *= S; u[k].y *= S; }
    } else {
        const float2* srcR = srcU + (((size_t)r0)<<10) + ro;
        #pragma unroll
        for (int k=0;k<8;++k) u[k] = srcR[lane + 128*k];
        __syncthreads();                   // tw ready for dif_ph1 below
    }
    #pragma unroll
    for (int k=0;k<8;++k) Tg[k] = Tz[gbase + lane + 128*k];
    // divided field (skip at head)
    #pragma unroll
    for (int k=0;k<8;++k){
        if (headU) r[k] = u[k];
        else {
            float inv = 1.0f/(Tg[k].x*Tg[k].x + Tg[k].y*Tg[k].y);
            float2 wc = cmulcj(u[k], Tg[k]);
            r[k] = make_float2(wc.x*inv, wc.y*inv);
        }
    }
    dif_ph1(r, tw, lane);
    st128l(A, ro, lane, r); __syncthreads();
    ld16l(A, ro, lane, r); dif_ph2(r, tw, m0);
    st16l(B, ro, lane, r); __syncthreads();
    ldfold_dif(B, ro, lane, tw, r); dif_reg(r);
    st8l(A, ro, lane, r); __syncthreads();
    twrite2(A, tid, dstU, r0, 1.0f);
    // ---- B chain: DIT ----
    load8g(srcB + (((size_t)r0)<<10) + ro, lane, r);
    dit_reg(r);
    st8l(B, ro, lane, r); __syncthreads();
    ldfold_dit(B, ro, lane, tw, r); dit_ph2(r, tw, m0);
    st16l(A, ro, lane, r); __syncthreads();
    ld128l(A, ro, lane, r); dit_ph1(r, tw, lane);
    // grad emit (into T plane) + premult conj(T)
    #pragma unroll
    for (int k=0;k<8;++k){
        float2 b = make_float2(S*r[k].x, S*r[k].y);
        float2 q = headU ? cmulcj(cmulcj(b, u[k]), Tg[k]) : cmulcj(b, u[k]);
        Tz[gbase + lane + 128*k] = make_float2(KAPPA*q.y, -KAPPA*q.x);
        r[k] = cmulcj(b, Tg[k]);
    }
    dif_ph1(r, tw, lane);
    st128l(B, ro, lane, r); __syncthreads();
    ld16l(B, ro, lane, r); dif_ph2(r, tw, m0);
    st16l(A, ro, lane, r); __syncthreads();
    ldfold_dif(A, ro, lane, tw, r); dif_reg(r);
    st8l(B, ro, lane, r); __syncthreads();
    twrite2(B, tid, dstB, r0, 1.0f);
}

// ---------- tail: finish both chains, grad[0] -> T plane 0 ----------
__global__ void __launch_bounds__(256) k_tail(
    const float2* __restrict__ srcU, const float2* __restrict__ srcB,
    float2* __restrict__ G0)
{
    __shared__ float2 A[2176], B[2176], tw[512];
    const int tid = threadIdx.x;
    fill_tw(tw, tid);
    const int row = tid>>7, lane = tid&127, ro = row<<10, m0 = lane&15;
    const int r0 = blockIdx.x*2;
    const size_t gbase = ((size_t)(r0+row))<<10;
    const float S = 1.0f/1024.0f;
    float2 u[8], r[8];
    load8g(srcU + (((size_t)r0)<<10) + ro, lane, u);
    dit_reg(u);
    st8l(A, ro, lane, u); __syncthreads();
    ldfold_dit(A, ro, lane, tw, u); dit_ph2(u, tw, m0);
    st16l(B, ro, lane, u); __syncthreads();
    ld128l(B, ro, lane, u); dit_ph1(u, tw, lane);
    load8g(srcB + (((size_t)r0)<<10) + ro, lane, r);
    dit_reg(r);
    st8l(A, ro, lane, r); __syncthreads();
    ldfold_dit(A, ro, lane, tw, r); dit_ph2(r, tw, m0);
    st16l(B, ro, lane, r); __syncthreads();
    ld128l(B, ro, lane, r); dit_ph1(r, tw, lane);
    #pragma unroll
    for (int k=0;k<8;++k){
        float2 b = make_float2(S*r[k].x, S*r[k].y);
        float2 w = make_float2(S*u[k].x, S*u[k].y);
        float2 q = cmulcj(b, w);
        G0[gbase + lane + 128*k] = make_float2(KAPPA*q.y, -KAPPA*q.x);
    }
}

__global__ void __launch_bounds__(256) k_merge(const float4* __restrict__ x,
                                               const float2* __restrict__ G,
                                               const float* __restrict__ alpha,
                                               float4* __restrict__ out){
    int idx = blockIdx.x*256 + threadIdx.x;
    float al = alpha[0];
    const float4* xp = x + (size_t)idx*8;
    float4 xv[8];
    #pragma unroll
    for (int k=0;k<8;++k) xv[k] = xp[k];
    const float* fx = (const float*)xv;
    float o[32];
    #pragma unroll
    for (int z=0;z<16;++z){
        float2 g = G[(size_t)z*NN + idx];
        o[z]    = fx[z]    - al*g.x;
        o[16+z] = fx[16+z] - al*g.y;
    }
    float4* op = out + (size_t)idx*8;
    #pragma unroll
    for (int k=0;k<8;++k)
        op[k] = make_float4(o[4*k], o[4*k+1], o[4*k+2], o[4*k+3]);
}

extern "C" void kernel_launch(void* const* d_in, const int* in_sizes, int n_in,
                              void* d_out, int out_size, void* d_ws, size_t ws_size,
                              hipStream_t stream)
{
    const float* x     = (const float*)d_in[0];
    const float* meas  = (const float*)d_in[1];
    const float* nail  = (const float*)d_in[2];
    const float* alpha = (const float*)d_in[3];

    if (ws_size < (size_t)23*NN*sizeof(float2)) return;

    float2* W   = (float2*)d_ws;
    float2* T   = W;                       // 16 planes; grads overwrite in place
    float2* KP  = W + (size_t)16*NN;
    float2* KF  = W + (size_t)17*NN;
    float2* U0  = W + (size_t)18*NN;
    float2* TAB = W + (size_t)19*NN;
    float2* TBB = W + (size_t)20*NN;
    float2* TAU = W + (size_t)21*NN;
    float2* TBU = W + (size_t)22*NN;

    k_kern<<<4096, 256, 0, stream>>>(KP, KF);
    k_T   <<<4096, 256, 0, stream>>>((const float4*)x, T);

    auto P2f = [&](const float2* km, int cj, int pup){
        k_pass2<<<512, 256, 0, stream>>>(TAB, TBB, nullptr, nullptr, km, cj, pup);
    };

    // ---------- forward + backprop mega-chain ----------
    k_head<<<512, 256, 0, stream>>>(TAB, T, nail);
    P2f(KP, 0, 0);
    for (int z = 1; z <= 14; ++z){
        k_junc<<<512, 256, 0, stream>>>(TBB, TAB, T + (size_t)z*NN, nullptr, nullptr, JT);
        P2f(KP, 0, 0);
    }
    k_junc<<<512, 256, 0, stream>>>(TBB, TAB, T + (size_t)15*NN, U0, nullptr, JT_WP);
    P2f(KF, 0, 0);
    k_junc<<<512, 256, 0, stream>>>(TBB, TAB, nullptr, nullptr, nullptr, JN);
    P2f(nullptr, 0, 1);
    k_junc<<<512, 256, 0, stream>>>(TBB, TAB, nullptr, nullptr, meas, JRESID);
    P2f(nullptr, 1, 1);
    k_junc<<<512, 256, 0, stream>>>(TBB, TAB, nullptr, nullptr, nullptr, JN);
    P2f(KF, 1, 0);

    // ---------- reverse loop: paired B/U per tile ----------
    for (int zz = 15; zz >= 1; --zz){
        k_rev<<<512, 256, 0, stream>>>(zz == 15 ? U0 : TBU, TAU, TBB, TAB,
                                       T + (size_t)zz*NN, zz == 15 ? 1 : 0);
        k_pass2<<<1024, 256, 0, stream>>>(TAB, TBB, TAU, TBU, KP, 1, 0);
    }
    k_tail<<<512, 256, 0, stream>>>(TBU, TBB, T);

    // ---------- merge: out = x - alpha*g, straight into d_out ----------
    k_merge<<<4096, 256, 0, stream>>>((const float4*)x, T, alpha, (float4*)d_out);
}